// Round 1
// baseline (274.541 us; speedup 1.0000x reference)
//
#include <hip/hip_runtime.h>

// Modulated deformable conv 3x3, in_ch=out_ch=1, stride=1, pad=1, dil=1.
// B=8, H=W=512. d_in order: depth, mask(weight), offset, w, b.
//
// R7: latency-bound restructure.
//  - R6 post-mortem: VGPR_Count=40 proves the 27-load batch NEVER materialized
//    (54 floats can't live in 40 VGPRs) -> loads were serialized load->wait->use.
//  - Fix: issue all 27 loads BEFORE the LDS staging loop. __syncthreads()'s
//    mandatory vmcnt(0) drain makes them free; post-barrier region is pure
//    VALU+LDS with zero vmem waits. 27 named f2 vars (no arrays -> no scratch),
//    sched_barrier(0) pin, __launch_bounds__(256,5) gives RA ~102-VGPR budget.
//  - Branchless inner loop: clamped-safe LDS sampling + oob flag; single
//    wave-uniform __any(oob) fixup at end (p ~ 1e-12) recomputes via global.
//  - LDS row stride padded 80->81 for bank decorrelation.

#define KK 9
#define PAD 1
#define H 512
#define W 512
#define HW (H * W)

#define TX 64
#define TY 8
#define HALO 8
#define LWL (TX + 2 * HALO)              // 80 logical columns
#define LH  (TY + 2 * HALO)              // 24 rows
#define LWS (LWL + 1)                    // 81 storage stride (bank decorrelation)
#define SAFE ((LH - 2) * LWS + (LWL - 2))  // 1860: max safe bilinear base index

typedef float f2 __attribute__((ext_vector_type(2)));

__device__ __forceinline__ float bilin_global(const float* __restrict__ img,
                                              float y, float x) {
    float y0f = floorf(y);
    float x0f = floorf(x);
    int y0 = (int)y0f;
    int x0 = (int)x0f;
    float wy = y - y0f;
    float wx = x - x0f;
    int y1 = y0 + 1;
    int x1 = x0 + 1;

    bool y0i = (y0 >= 0) & (y0 < H);
    bool y1i = (y1 >= 0) & (y1 < H);
    bool x0i = (x0 >= 0) & (x0 < W);
    bool x1i = (x1 >= 0) & (x1 < W);

    int y0c = min(max(y0, 0), H - 1);
    int y1c = min(max(y1, 0), H - 1);
    int x0c = min(max(x0, 0), W - 1);
    int x1c = min(max(x1, 0), W - 1);

    float v00 = (y0i & x0i) ? img[y0c * W + x0c] : 0.0f;
    float v01 = (y0i & x1i) ? img[y0c * W + x1c] : 0.0f;
    float v10 = (y1i & x0i) ? img[y1c * W + x0c] : 0.0f;
    float v11 = (y1i & x1i) ? img[y1c * W + x1c] : 0.0f;

    float omwy = 1.0f - wy;
    float omwx = 1.0f - wx;
    return fmaf(v00 * omwy, omwx,
           fmaf(v01 * omwy, wx,
           fmaf(v10 * wy,   omwx, v11 * wy * wx)));
}

// Branchless tile sample. Coordinates are TILE-RELATIVE floats. Out-of-tile
// lanes read a clamped (safe, garbage) address and set oob; fixup recomputes.
__device__ __forceinline__ float sample_nb(const float* S, float syr, float sxr,
                                           int& oob) {
    const float y0f = floorf(syr);
    const float x0f = floorf(sxr);
    const float wy = syr - y0f;
    const float wx = sxr - x0f;
    const int ly = (int)y0f;
    const int lx = (int)x0f;
    oob |= (int)(((unsigned)ly >= (unsigned)(LH - 1)) |
                 ((unsigned)lx >= (unsigned)(LWL - 1)));
    unsigned su = (unsigned)(ly * LWS + lx);
    su = su < (unsigned)SAFE ? su : (unsigned)SAFE;   // v_min_u32: always-safe read
    const float v00 = S[su];
    const float v01 = S[su + 1];
    const float v10 = S[su + LWS];
    const float v11 = S[su + LWS + 1];
    const float omwy = 1.0f - wy;
    const float omwx = 1.0f - wx;
    return fmaf(v00 * omwy, omwx,
           fmaf(v01 * omwy, wx,
           fmaf(v10 * wy,   omwx, v11 * wy * wx)));
}

__global__ __launch_bounds__(256, 5) void dcn_kernel(
    const float* __restrict__ depth,
    const float* __restrict__ mask,
    const float* __restrict__ offset,
    const float* __restrict__ w9,
    const float* __restrict__ bias,
    float* __restrict__ out) {
    __shared__ float S[LH * LWS];

    const int b  = blockIdx.z;
    const int bx = blockIdx.x;
    const int by = blockIdx.y;
    const int tX0 = bx * TX - HALO;
    const int tY0 = by * TY - HALO;

    const float* __restrict__ img = depth + (long)b * HW;

    // 2 consecutive px/thread
    const int xp = threadIdx.x & 31;        // x-pair 0..31
    const int yr = threadIdx.x >> 5;        // row 0..7
    const int tx = bx * TX + 2 * xp;
    const int ty = by * TY + yr;
    const int pix = ty * W + tx;

    const float* __restrict__ msk = mask   + ((long)b * KK)     * HW + pix;
    const float* __restrict__ off = offset + ((long)b * 2 * KK) * HW + pix;

    // --- issue ALL 27 streaming dwordx2 loads FIRST; their latency hides under
    // the LDS staging + the barrier's mandatory vmcnt(0) drain. Named scalars:
    // no arrays, no scratch, no partial-unroll ambiguity. ---
    f2 dy0, dy1, dy2, dy3, dy4, dy5, dy6, dy7, dy8;
    f2 dx0, dx1, dx2, dx3, dx4, dx5, dx6, dx7, dx8;
    f2 m0, m1, m2, m3, m4, m5, m6, m7, m8;
#define LDT(k)                                              \
    dy##k = *(const f2*)(off + (2 * k) * HW);               \
    dx##k = *(const f2*)(off + (2 * k + 1) * HW);           \
    m##k  = *(const f2*)(msk + k * HW);
    LDT(0) LDT(1) LDT(2) LDT(3) LDT(4) LDT(5) LDT(6) LDT(7) LDT(8)
#undef LDT
    // Pin: all 27 loads are issued before anything below.
    __builtin_amdgcn_sched_barrier(0);

    // --- stage depth tile (+halo) into LDS; out-of-image cells = 0 ---
    for (int i = threadIdx.x; i < LH * LWL; i += 256) {
        const int ly = i / LWL;
        const int lx = i - ly * LWL;
        const int gy = tY0 + ly;
        const int gx = tX0 + lx;
        float v = 0.0f;
        if (((unsigned)gy < (unsigned)H) & ((unsigned)gx < (unsigned)W))
            v = img[gy * W + gx];
        S[ly * LWS + lx] = v;
    }
    __syncthreads();   // vmcnt(0) drain: all payload regs are ready here

    const float bs = bias[0];
    float a0 = bs, a1 = bs;
    int oob = 0;
    // Tile-relative sample base: (ty - PAD) - tY0 = yr + HALO - PAD
    const float sybr = (float)(yr + HALO - PAD);
    const float sxbr = (float)(2 * xp + HALO - PAD);

    // --- pure VALU+LDS consume: branchless, fully unrolled ---
#define CTAP(k, KYC, KXC)                                                     \
    {                                                                         \
        const float wk = w9[k];                                               \
        const float syA = sybr + (float)(KYC) + dy##k.x;                      \
        const float sxA = sxbr + (float)(KXC) + dx##k.x;                      \
        a0 = fmaf(sample_nb(S, syA, sxA, oob), m##k.x * wk, a0);              \
        const float syB = sybr + (float)(KYC) + dy##k.y;                      \
        const float sxB = sxbr + (float)(KXC) + 1.0f + dx##k.y;               \
        a1 = fmaf(sample_nb(S, syB, sxB, oob), m##k.y * wk, a1);              \
    }
    CTAP(0, 0, 0) CTAP(1, 0, 1) CTAP(2, 0, 2)
    CTAP(3, 1, 0) CTAP(4, 1, 1) CTAP(5, 1, 2)
    CTAP(6, 2, 0) CTAP(7, 2, 1) CTAP(8, 2, 2)
#undef CTAP

    // --- rare fixup: any lane whose any sample left the tile recomputes the
    // whole pixel pair via the global path. Wave-uniform skip in the common
    // case (p ~ 1e-12). Reloads payload from global so the 54-float batch's
    // liveness does NOT extend across this block. ---
    if (__builtin_expect(__any(oob), 0)) {
        if (oob) {
            a0 = bs;
            a1 = bs;
#pragma unroll 1
            for (int k = 0; k < KK; ++k) {
                const int ky = k / 3;
                const int kx = k - 3 * ky;
                const float wk = w9[k];
                const float fdy0 = off[(2 * k) * HW];
                const float fdy1 = off[(2 * k) * HW + 1];
                const float fdx0 = off[(2 * k + 1) * HW];
                const float fdx1 = off[(2 * k + 1) * HW + 1];
                const float fm0 = msk[k * HW];
                const float fm1 = msk[k * HW + 1];
                const float syA = (float)(ty - PAD + ky) + fdy0;
                const float sxA = (float)(tx - PAD + kx) + fdx0;
                a0 = fmaf(bilin_global(img, syA, sxA), fm0 * wk, a0);
                const float syB = (float)(ty - PAD + ky) + fdy1;
                const float sxB = (float)(tx - PAD + kx + 1) + fdx1;
                a1 = fmaf(bilin_global(img, syB, sxB), fm1 * wk, a1);
            }
        }
    }

    f2 r;
    r.x = a0;
    r.y = a1;
    *(f2*)(out + (long)b * HW + pix) = r;
}

extern "C" void kernel_launch(void* const* d_in, const int* in_sizes, int n_in,
                              void* d_out, int out_size, void* d_ws, size_t ws_size,
                              hipStream_t stream) {
    const float* depth  = (const float*)d_in[0];
    const float* mask   = (const float*)d_in[1];   // reference's "weight" arg = modulation mask
    const float* offset = (const float*)d_in[2];
    const float* w9     = (const float*)d_in[3];
    const float* bias   = (const float*)d_in[4];
    float* out = (float*)d_out;

    const int B = in_sizes[0] / HW;   // = 8

    dim3 block(256);
    dim3 grid(W / TX, H / TY, B);     // (8, 64, 8)
    dcn_kernel<<<grid, block, 0, stream>>>(depth, mask, offset, w9, bias, out);
}

// Round 2
// 271.700 us; speedup vs baseline: 1.0105x; 1.0105x over previous
//
#include <hip/hip_runtime.h>

// Modulated deformable conv 3x3, in_ch=out_ch=1, stride=1, pad=1, dil=1.
// B=8, H=W=512. d_in order: depth, mask(weight), offset, w, b.
//
// R8: force the load batch with a volatile register-tied asm pin.
//  - R7 post-mortem: VGPR_Count=44 -> sched_barrier(0) did NOT stop
//    MachineSink from sinking the 27 payload loads past the barrier into the
//    consume block; loads still serialized load->wait->use (9 exposed
//    latencies/wave). sched_barrier only fences within a scheduling region.
//  - Fix: asm volatile("" : "+v"(...)) naming ALL 27 payload values, placed
//    just before __syncthreads(). Volatile asm can't be sunk; tied operands
//    can't be rematerialized -> RA must keep 54 floats live across the
//    barrier -> all 27 loads issue up front, drained ONCE by the barrier's
//    vmcnt(0).
//  - Staging loop: fully unrolled 8 rounds, unconditional clamped-address
//    loads (select-0 after) so the 8 staging loads batch with the payload.
//    One exposed memory latency per wave total.
//  - __launch_bounds__(256,4): VGPR cap 128 (16 waves/CU, same occupancy).

#define KK 9
#define PAD 1
#define H 512
#define W 512
#define HW (H * W)

#define TX 64
#define TY 8
#define HALO 8
#define LWL (TX + 2 * HALO)              // 80 logical columns
#define LH  (TY + 2 * HALO)              // 24 rows
#define LWS (LWL + 1)                    // 81 storage stride (bank decorrelation)
#define NSTAGE (LH * LWL)                // 1920 logical stage elements
#define SAFE ((LH - 2) * LWS + (LWL - 2))  // 1860: max safe bilinear base index
#define TRASH (LH * LWS - 1)             // 1943: write-only garbage slot (never read)

typedef float f2 __attribute__((ext_vector_type(2)));

__device__ __forceinline__ float bilin_global(const float* __restrict__ img,
                                              float y, float x) {
    float y0f = floorf(y);
    float x0f = floorf(x);
    int y0 = (int)y0f;
    int x0 = (int)x0f;
    float wy = y - y0f;
    float wx = x - x0f;
    int y1 = y0 + 1;
    int x1 = x0 + 1;

    bool y0i = (y0 >= 0) & (y0 < H);
    bool y1i = (y1 >= 0) & (y1 < H);
    bool x0i = (x0 >= 0) & (x0 < W);
    bool x1i = (x1 >= 0) & (x1 < W);

    int y0c = min(max(y0, 0), H - 1);
    int y1c = min(max(y1, 0), H - 1);
    int x0c = min(max(x0, 0), W - 1);
    int x1c = min(max(x1, 0), W - 1);

    float v00 = (y0i & x0i) ? img[y0c * W + x0c] : 0.0f;
    float v01 = (y0i & x1i) ? img[y0c * W + x1c] : 0.0f;
    float v10 = (y1i & x0i) ? img[y1c * W + x0c] : 0.0f;
    float v11 = (y1i & x1i) ? img[y1c * W + x1c] : 0.0f;

    float omwy = 1.0f - wy;
    float omwx = 1.0f - wx;
    return fmaf(v00 * omwy, omwx,
           fmaf(v01 * omwy, wx,
           fmaf(v10 * wy,   omwx, v11 * wy * wx)));
}

// Branchless tile sample. Coordinates are TILE-RELATIVE floats. Out-of-tile
// lanes read a clamped (safe, garbage) address and set oob; fixup recomputes.
__device__ __forceinline__ float sample_nb(const float* S, float syr, float sxr,
                                           int& oob) {
    const float y0f = floorf(syr);
    const float x0f = floorf(sxr);
    const float wy = syr - y0f;
    const float wx = sxr - x0f;
    const int ly = (int)y0f;
    const int lx = (int)x0f;
    oob |= (int)(((unsigned)ly >= (unsigned)(LH - 1)) |
                 ((unsigned)lx >= (unsigned)(LWL - 1)));
    unsigned su = (unsigned)(ly * LWS + lx);
    su = su < (unsigned)SAFE ? su : (unsigned)SAFE;   // v_min_u32: always-safe read
    const float v00 = S[su];
    const float v01 = S[su + 1];
    const float v10 = S[su + LWS];
    const float v11 = S[su + LWS + 1];
    const float omwy = 1.0f - wy;
    const float omwx = 1.0f - wx;
    return fmaf(v00 * omwy, omwx,
           fmaf(v01 * omwy, wx,
           fmaf(v10 * wy,   omwx, v11 * wy * wx)));
}

__global__ __launch_bounds__(256, 4) void dcn_kernel(
    const float* __restrict__ depth,
    const float* __restrict__ mask,
    const float* __restrict__ offset,
    const float* __restrict__ w9,
    const float* __restrict__ bias,
    float* __restrict__ out) {
    __shared__ float S[LH * LWS];

    const int b  = blockIdx.z;
    const int bx = blockIdx.x;
    const int by = blockIdx.y;
    const int tX0 = bx * TX - HALO;
    const int tY0 = by * TY - HALO;

    const float* __restrict__ img = depth + (long)b * HW;

    // 2 consecutive px/thread
    const int xp = threadIdx.x & 31;        // x-pair 0..31
    const int yr = threadIdx.x >> 5;        // row 0..7
    const int tx = bx * TX + 2 * xp;
    const int ty = by * TY + yr;
    const int pix = ty * W + tx;

    const float* __restrict__ msk = mask   + ((long)b * KK)     * HW + pix;
    const float* __restrict__ off = offset + ((long)b * 2 * KK) * HW + pix;

    // uniform taps: scalar loads, issued early
    const float wk0 = w9[0], wk1 = w9[1], wk2 = w9[2];
    const float wk3 = w9[3], wk4 = w9[4], wk5 = w9[5];
    const float wk6 = w9[6], wk7 = w9[7], wk8 = w9[8];
    const float bs = bias[0];

    // --- issue ALL 27 streaming dwordx2 payload loads ---
    f2 dy0, dy1, dy2, dy3, dy4, dy5, dy6, dy7, dy8;
    f2 dx0, dx1, dx2, dx3, dx4, dx5, dx6, dx7, dx8;
    f2 m0, m1, m2, m3, m4, m5, m6, m7, m8;
#define LDT(k)                                              \
    dy##k = *(const f2*)(off + (2 * k) * HW);               \
    dx##k = *(const f2*)(off + (2 * k + 1) * HW);           \
    m##k  = *(const f2*)(msk + k * HW);
    LDT(0) LDT(1) LDT(2) LDT(3) LDT(4) LDT(5) LDT(6) LDT(7) LDT(8)
#undef LDT

    // --- stage depth tile (+halo): batched. 8 unconditional clamped loads,
    // then 8 ds_writes (select-0 for out-of-image). ---
    float sv[8];
    int   si[8];
    int   sok[8];
    #pragma unroll
    for (int j = 0; j < 8; ++j) {
        const int i  = (int)threadIdx.x + j * 256;
        const int ly = i / LWL;
        const int lx = i - ly * LWL;
        const int gy = tY0 + ly;
        const int gx = tX0 + lx;
        const int inimg = (int)(((unsigned)gy < (unsigned)H) &
                                ((unsigned)gx < (unsigned)W));
        const int gidx = inimg ? (gy * W + gx) : 0;   // clamped: load always legal
        sv[j]  = img[gidx];                           // unconditional -> batchable
        sok[j] = inimg;
        si[j]  = (i < NSTAGE) ? (ly * LWS + lx) : TRASH;
    }
    #pragma unroll
    for (int j = 0; j < 8; ++j)
        S[si[j]] = sok[j] ? sv[j] : 0.0f;

    // --- THE PIN: volatile asm with all 27 payload values register-tied.
    // Cannot be sunk; forces the whole 54-float batch live in VGPRs here,
    // i.e. all loads issued above, drained once by the barrier. ---
    asm volatile(""
        : "+v"(dy0), "+v"(dx0), "+v"(m0),
          "+v"(dy1), "+v"(dx1), "+v"(m1),
          "+v"(dy2), "+v"(dx2), "+v"(m2),
          "+v"(dy3), "+v"(dx3), "+v"(m3),
          "+v"(dy4), "+v"(dx4), "+v"(m4),
          "+v"(dy5), "+v"(dx5), "+v"(m5),
          "+v"(dy6), "+v"(dx6), "+v"(m6),
          "+v"(dy7), "+v"(dx7), "+v"(m7),
          "+v"(dy8), "+v"(dx8), "+v"(m8));

    __syncthreads();   // vmcnt(0)+lgkmcnt(0) drain: tile + payload all ready

    float a0 = bs, a1 = bs;
    int oob = 0;
    // Tile-relative sample base: (ty - PAD) - tY0 = yr + HALO - PAD
    const float sybr = (float)(yr + HALO - PAD);
    const float sxbr = (float)(2 * xp + HALO - PAD);

    // --- pure VALU+LDS consume: branchless, fully unrolled, zero vmem waits ---
#define CTAP(k, KYC, KXC, WK)                                                 \
    {                                                                         \
        const float syA = sybr + (float)(KYC) + dy##k.x;                      \
        const float sxA = sxbr + (float)(KXC) + dx##k.x;                      \
        a0 = fmaf(sample_nb(S, syA, sxA, oob), m##k.x * (WK), a0);            \
        const float syB = sybr + (float)(KYC) + dy##k.y;                      \
        const float sxB = sxbr + (float)(KXC) + 1.0f + dx##k.y;               \
        a1 = fmaf(sample_nb(S, syB, sxB, oob), m##k.y * (WK), a1);            \
    }
    CTAP(0, 0, 0, wk0) CTAP(1, 0, 1, wk1) CTAP(2, 0, 2, wk2)
    CTAP(3, 1, 0, wk3) CTAP(4, 1, 1, wk4) CTAP(5, 1, 2, wk5)
    CTAP(6, 2, 0, wk6) CTAP(7, 2, 1, wk7) CTAP(8, 2, 2, wk8)
#undef CTAP

    // --- rare fixup: any lane whose any sample left the tile recomputes the
    // whole pixel pair via the global path (p ~ 1e-12; wave-uniform skip). ---
    if (__builtin_expect(__any(oob), 0)) {
        if (oob) {
            a0 = bs;
            a1 = bs;
#pragma unroll 1
            for (int k = 0; k < KK; ++k) {
                const int ky = k / 3;
                const int kx = k - 3 * ky;
                const float wk = w9[k];
                const float fdy0 = off[(2 * k) * HW];
                const float fdy1 = off[(2 * k) * HW + 1];
                const float fdx0 = off[(2 * k + 1) * HW];
                const float fdx1 = off[(2 * k + 1) * HW + 1];
                const float fm0 = msk[k * HW];
                const float fm1 = msk[k * HW + 1];
                const float syA = (float)(ty - PAD + ky) + fdy0;
                const float sxA = (float)(tx - PAD + kx) + fdx0;
                a0 = fmaf(bilin_global(img, syA, sxA), fm0 * wk, a0);
                const float syB = (float)(ty - PAD + ky) + fdy1;
                const float sxB = (float)(tx - PAD + kx + 1) + fdx1;
                a1 = fmaf(bilin_global(img, syB, sxB), fm1 * wk, a1);
            }
        }
    }

    f2 r;
    r.x = a0;
    r.y = a1;
    *(f2*)(out + (long)b * HW + pix) = r;
}

extern "C" void kernel_launch(void* const* d_in, const int* in_sizes, int n_in,
                              void* d_out, int out_size, void* d_ws, size_t ws_size,
                              hipStream_t stream) {
    const float* depth  = (const float*)d_in[0];
    const float* mask   = (const float*)d_in[1];   // reference's "weight" arg = modulation mask
    const float* offset = (const float*)d_in[2];
    const float* w9     = (const float*)d_in[3];
    const float* bias   = (const float*)d_in[4];
    float* out = (float*)d_out;

    const int B = in_sizes[0] / HW;   // = 8

    dim3 block(256);
    dim3 grid(W / TX, H / TY, B);     // (8, 64, 8)
    dcn_kernel<<<grid, block, 0, stream>>>(depth, mask, offset, w9, bias, out);
}